// Round 4
// baseline (28837.170 us; speedup 1.0000x reference)
//
#include <hip/hip_runtime.h>
#include <hip/hip_bf16.h>

#define BB 32
#define TD 800
#define TO 400
#define AA 256
#define EE 512
#define VV 8192
#define G4 1024
#define MM (BB*TO)        // 12800
#define NEGE -1e9f
#define KTP 1024          // padded Td (t index) for kT2
#define VTP 512           // padded t2 rows for v2

typedef _Float16 h2_t __attribute__((ext_vector_type(2)));

__device__ __forceinline__ float sigm(float x){ return 1.f/(1.f+expf(-x)); }

__device__ __forceinline__ uint f2h2(float a, float b){
  _Float16 ha = (_Float16)a, hb = (_Float16)b;
  ushort ua = __builtin_bit_cast(ushort, ha), ub = __builtin_bit_cast(ushort, hb);
  return (uint)ua | ((uint)ub << 16);
}

__device__ __forceinline__ float dot2(uint a, uint b, float c){
#if defined(__has_builtin) && __has_builtin(__builtin_amdgcn_fdot2)
  return __builtin_amdgcn_fdot2(__builtin_bit_cast(h2_t, a),
                                __builtin_bit_cast(h2_t, b), c, false);
#else
  h2_t ha = __builtin_bit_cast(h2_t, a), hb = __builtin_bit_cast(h2_t, b);
  return c + (float)ha[0]*(float)hb[0] + (float)ha[1]*(float)hb[1];
#endif
}

__device__ __forceinline__ float decode_ptf(const void* p){
  int w = *(const int*)p;
  if (w >= 0 && w < 1048576) return (float)w;
  return __int_as_float(w);
}

// ---- W2[k2][j] = half2(Wcat[2k2][j], Wcat[2k2+1][j]); Wcat[k][j] = k<256 ? Wih[j][512+k] : Whh[j][k-256]
//      WihxT[e][j] = Wih[j][e]  (fp32, fallback path only)
__global__ void kprep_w(const float* __restrict__ Wih, const float* __restrict__ Whh,
                        uint* __restrict__ W2, float* __restrict__ WihxT){
  int id = blockIdx.x*blockDim.x + threadIdx.x;
  const int total = 256*G4 + EE*G4;
  for (; id < total; id += gridDim.x*blockDim.x){
    if (id < 256*G4){
      int k2 = id >> 10, j = id & 1023;
      int k0 = 2*k2, k1 = 2*k2+1;
      float f0 = (k0 < AA) ? Wih[j*768 + EE + k0] : Whh[j*AA + (k0-AA)];
      float f1 = (k1 < AA) ? Wih[j*768 + EE + k1] : Whh[j*AA + (k1-AA)];
      W2[id] = f2h2(f0, f1);
    } else {
      int i2 = id - 256*G4;
      int e = i2 >> 10, j = i2 & 1023;
      WihxT[i2] = Wih[j*768 + e];
    }
  }
}

// ---- kT2[b][a2][t] = half2(k[b][t][2a2], k[b][t][2a2+1]) padded t<1024
//      v2[b][t2][a]  = half2(v[b][2t2][a], v[b][2t2+1][a]) padded t2<512
__global__ void kprep_kv(const float* __restrict__ k, const float* __restrict__ v,
                         uint* __restrict__ kT2, uint* __restrict__ v2){
  int id = blockIdx.x*blockDim.x + threadIdx.x;
  const int nk = BB*128*KTP;
  const int nv = BB*VTP*AA;
  for (; id < nk + nv; id += gridDim.x*blockDim.x){
    if (id < nk){
      int t = id & (KTP-1);
      int rest = id >> 10;
      int a2 = rest & 127;
      int b = rest >> 7;
      float f0 = 0.f, f1 = 0.f;
      if (t < TD){
        f0 = k[((size_t)b*TD + t)*AA + 2*a2];
        f1 = k[((size_t)b*TD + t)*AA + 2*a2+1];
      }
      kT2[id] = f2h2(f0, f1);
    } else {
      int i2 = id - nk;
      int a = i2 & (AA-1);
      int rest = i2 >> 8;
      int t2 = rest & (VTP-1);
      int b = rest >> 9;
      int t0 = 2*t2, t1 = 2*t2+1;
      float f0 = (t0 < TD) ? v[((size_t)b*TD + t0)*AA + a] : 0.f;
      float f1 = (t1 < TD) ? v[((size_t)b*TD + t1)*AA + a] : 0.f;
      v2[i2] = f2h2(f0, f1);
    }
  }
}

// ---- XG[m][j] = sum_e emb[gt[m]][e]*WihxT[e][j] + b_ih[j] + b_hh[j]   (fp32)
__global__ __launch_bounds__(256) void kxg(const int* __restrict__ gt,
                     const float* __restrict__ embW,
                     const float* __restrict__ WihxT, const float* __restrict__ bih,
                     const float* __restrict__ bhh, float* __restrict__ XG){
  __shared__ float Xs[16][64];
  __shared__ int toks[16];
  const int m0 = blockIdx.x * 16;
  const int j0 = blockIdx.y * 256 + (threadIdx.x & 63)*4;
  const int r0 = (threadIdx.x >> 6) * 4;
  float acc[4][4];
  #pragma unroll
  for (int r=0;r<4;++r){ acc[r][0]=acc[r][1]=acc[r][2]=acc[r][3]=0.f; }
  if (threadIdx.x < 16) toks[threadIdx.x] = gt[m0 + threadIdx.x];
  __syncthreads();
  for (int kc=0; kc<EE; kc+=64){
    {
      int lr = threadIdx.x >> 4;
      int lq = threadIdx.x & 15;
      const float4 xv = *(const float4*)(embW + (size_t)toks[lr]*EE + kc + lq*4);
      Xs[lr][lq*4+0]=xv.x; Xs[lr][lq*4+1]=xv.y; Xs[lr][lq*4+2]=xv.z; Xs[lr][lq*4+3]=xv.w;
    }
    __syncthreads();
    #pragma unroll 4
    for (int kk=0; kk<64; ++kk){
      const float4 wv = *(const float4*)(WihxT + (size_t)(kc+kk)*G4 + j0);
      #pragma unroll
      for (int r=0;r<4;++r){
        float xs = Xs[r0+r][kk];
        acc[r][0] += wv.x*xs; acc[r][1] += wv.y*xs;
        acc[r][2] += wv.z*xs; acc[r][3] += wv.w*xs;
      }
    }
    __syncthreads();
  }
  const float4 b1 = *(const float4*)(bih + j0);
  const float4 b2 = *(const float4*)(bhh + j0);
  #pragma unroll
  for (int r=0;r<4;++r){
    float4 o4 = make_float4(acc[r][0]+b1.x+b2.x, acc[r][1]+b1.y+b2.y,
                            acc[r][2]+b1.z+b2.z, acc[r][3]+b1.w+b2.w);
    *(float4*)(XG + (size_t)(m0+r0+r)*G4 + j0) = o4;
  }
}

// ---- sequential recurrence, one block per batch, f16 dot2 everywhere
__global__ __launch_bounds__(1024) void kseq(
    const uint* __restrict__ kT2, const uint* __restrict__ v2,
    const int* __restrict__ enc, const void* __restrict__ ptfp,
    const uint* __restrict__ W2, const float* __restrict__ embW,
    const float* __restrict__ charb, const float* __restrict__ u,
    const float* __restrict__ XG, const float* __restrict__ WihxT,
    const float* __restrict__ bih, const float* __restrict__ bhh,
    float* __restrict__ HC)
{
  __shared__ float s_s[EE];        // ctx(0..255) || h(256..511)  (fp32, fallback/need_pred)
  __shared__ uint  s2u[256];       // half2 pairs: [0..127]=ctx pairs, [128..255]=h pairs
  __shared__ uint  p2u[512];       // half2 pairs of softmax numerators
  __shared__ float c_s[AA];
  __shared__ float part[4*G4];     // 16KB: gates/energy [4][1024]; ctx [16][256]
  __shared__ float p_s[G4];        // fallback xg buffer only
  __shared__ float x_s[EE];
  __shared__ float red_m[16], red_s[16];
  __shared__ float rv[16];
  __shared__ int   ri[16];
  __shared__ int   pred_s;

  const int b = blockIdx.x;
  const int tid = threadIdx.x;
  const int lane = tid & 63;
  const int wvi = tid >> 6;
  const int len = enc[b];
  const int len2 = (len + 1) >> 1;
  const float ptf = decode_ptf(ptfp);

  if (tid < AA){ s_s[tid]=0.f; s_s[AA+tid]=0.f; c_s[tid]=0.f; s2u[tid]=0u; }
  if (tid == 0) pred_s = 0;
  __syncthreads();

  const int j4 = tid & 255;        // gates: float4-of-j
  const int kq = tid >> 8;         // gates: k2 quarter (64 rows)
  const int tq = tid & 255;        // energy: 4 consecutive t
  const int aq = tid >> 8;         // energy: a2 quarter (32 rows)
  const int a4 = tid & 63;         // ctx: float4-of-a
  const int tg = tid >> 6;         // ctx: t2 group 0..15

  for (int t=0; t<TO; ++t){
    const int m = b*TO + t;
    const bool tf = (u[t] < ptf);

    if (!tf){
      // fallback (never taken with p_tf=1): xg into p_s
      if (tid < EE) x_s[tid] = embW[(size_t)pred_s*EE + tid];
      __syncthreads();
      float a0 = bih[tid] + bhh[tid];
      for (int e=0;e<EE;++e) a0 += x_s[e]*WihxT[(size_t)e*G4 + tid];
      p_s[tid] = a0;
      __syncthreads();
    }

    // ---- gates partials: part[kq][j] = sum over 64 k2-rows of dot2(W2, s2)
    {
      const uint4* wp = (const uint4*)W2 + (size_t)(kq*64)*256 + j4;
      const uint* sp = s2u + kq*64;
      float4 acA = make_float4(0,0,0,0), acB = make_float4(0,0,0,0);
      float4 acC = make_float4(0,0,0,0), acD = make_float4(0,0,0,0);
      #pragma unroll 2
      for (int r=0; r<16; ++r){
        uint4 w0 = wp[0], w1 = wp[256], w2 = wp[512], w3 = wp[768];
        wp += 1024;
        uint s0 = sp[r*4+0], s1 = sp[r*4+1], s2 = sp[r*4+2], s3 = sp[r*4+3];
        acA.x = dot2(w0.x,s0,acA.x); acA.y = dot2(w0.y,s0,acA.y);
        acA.z = dot2(w0.z,s0,acA.z); acA.w = dot2(w0.w,s0,acA.w);
        acB.x = dot2(w1.x,s1,acB.x); acB.y = dot2(w1.y,s1,acB.y);
        acB.z = dot2(w1.z,s1,acB.z); acB.w = dot2(w1.w,s1,acB.w);
        acC.x = dot2(w2.x,s2,acC.x); acC.y = dot2(w2.y,s2,acC.y);
        acC.z = dot2(w2.z,s2,acC.z); acC.w = dot2(w2.w,s2,acC.w);
        acD.x = dot2(w3.x,s3,acD.x); acD.y = dot2(w3.y,s3,acD.y);
        acD.z = dot2(w3.z,s3,acD.z); acD.w = dot2(w3.w,s3,acD.w);
      }
      float4 ac = make_float4(acA.x+acB.x+acC.x+acD.x, acA.y+acB.y+acC.y+acD.y,
                              acA.z+acB.z+acC.z+acD.z, acA.w+acB.w+acC.w+acD.w);
      *(float4*)(part + (size_t)kq*G4 + j4*4) = ac;
    }
    __syncthreads();

    // ---- LSTM pointwise
    if (tid < AA){
      float bi_, bf_, bg_, bo_;
      if (tf){
        const float* xb = XG + (size_t)m*G4;
        bi_ = xb[tid]; bf_ = xb[AA+tid]; bg_ = xb[2*AA+tid]; bo_ = xb[3*AA+tid];
      } else {
        bi_ = p_s[tid]; bf_ = p_s[AA+tid]; bg_ = p_s[2*AA+tid]; bo_ = p_s[3*AA+tid];
      }
      float gi=bi_, gf=bf_, gg=bg_, go=bo_;
      #pragma unroll
      for (int q=0;q<4;++q){
        const float* pp = part + q*G4;
        gi += pp[tid]; gf += pp[AA+tid]; gg += pp[2*AA+tid]; go += pp[3*AA+tid];
      }
      float cn = sigm(gf)*c_s[tid] + sigm(gi)*tanhf(gg);
      float hn = sigm(go)*tanhf(cn);
      c_s[tid] = cn;
      s_s[AA+tid] = hn;
      HC[(size_t)m*EE + tid] = hn;
      float hp = __shfl_xor(hn, 1);
      if (!(tid & 1)) s2u[128 + (tid>>1)] = f2h2(hn, hp);
    }
    __syncthreads();

    // ---- energy partials: part[aq][t'] over 4 consecutive t, 32 a2-rows
    {
      float4 acA = make_float4(0,0,0,0), acB = make_float4(0,0,0,0);
      float4 acC = make_float4(0,0,0,0), acD = make_float4(0,0,0,0);
      if (tq*4 < len){
        const uint4* kp = (const uint4*)kT2 + ((size_t)b*128 + aq*32)*256 + tq;
        const uint* sp = s2u + 128 + aq*32;
        #pragma unroll 2
        for (int r=0; r<8; ++r){
          uint4 k0 = kp[0], k1 = kp[256], k2 = kp[512], k3 = kp[768];
          kp += 1024;
          uint s0 = sp[r*4+0], s1 = sp[r*4+1], s2 = sp[r*4+2], s3 = sp[r*4+3];
          acA.x = dot2(k0.x,s0,acA.x); acA.y = dot2(k0.y,s0,acA.y);
          acA.z = dot2(k0.z,s0,acA.z); acA.w = dot2(k0.w,s0,acA.w);
          acB.x = dot2(k1.x,s1,acB.x); acB.y = dot2(k1.y,s1,acB.y);
          acB.z = dot2(k1.z,s1,acB.z); acB.w = dot2(k1.w,s1,acB.w);
          acC.x = dot2(k2.x,s2,acC.x); acC.y = dot2(k2.y,s2,acC.y);
          acC.z = dot2(k2.z,s2,acC.z); acC.w = dot2(k2.w,s2,acC.w);
          acD.x = dot2(k3.x,s3,acD.x); acD.y = dot2(k3.y,s3,acD.y);
          acD.z = dot2(k3.z,s3,acD.z); acD.w = dot2(k3.w,s3,acD.w);
        }
      }
      float4 ac = make_float4(acA.x+acB.x+acC.x+acD.x, acA.y+acB.y+acC.y+acD.y,
                              acA.z+acB.z+acC.z+acD.z, acA.w+acB.w+acC.w+acD.w);
      *(float4*)(part + (size_t)aq*G4 + tq*4) = ac;
    }
    __syncthreads();

    // ---- softmax over t' = tid
    float ev = NEGE;
    if (tid < len) ev = part[tid] + part[G4+tid] + part[2*G4+tid] + part[3*G4+tid];
    float mx = ev;
    #pragma unroll
    for (int o=1;o<64;o<<=1) mx = fmaxf(mx, __shfl_xor(mx,o));
    if (lane==0) red_m[wvi] = mx;
    __syncthreads();
    float M = red_m[0];
    #pragma unroll
    for (int i2=1;i2<16;++i2) M = fmaxf(M, red_m[i2]);
    float p = expf(ev - M);          // masked -> 0
    float ppart = __shfl_xor(p, 1);
    if (!(tid & 1)) p2u[tid>>1] = f2h2(p, ppart);
    float sv = p;
    #pragma unroll
    for (int o=1;o<64;o<<=1) sv += __shfl_xor(sv,o);
    if (lane==0) red_s[wvi] = sv;
    __syncthreads();
    float S = 0.f;
    #pragma unroll
    for (int i2=0;i2<16;++i2) S += red_s[i2];

    // ---- ctx partials: part[tg][a], dot2 over t-pairs
    {
      float4 ac = make_float4(0,0,0,0);
      const uint4* vp = (const uint4*)v2 + (size_t)b*VTP*64 + a4;
      #pragma unroll 4
      for (int t2=tg; t2<len2; t2+=16){
        uint4 vv = vp[(size_t)t2*64];
        uint pp = p2u[t2];
        ac.x = dot2(vv.x, pp, ac.x); ac.y = dot2(vv.y, pp, ac.y);
        ac.z = dot2(vv.z, pp, ac.z); ac.w = dot2(vv.w, pp, ac.w);
      }
      *(float4*)(part + (size_t)tg*AA + a4*4) = ac;
    }
    __syncthreads();
    if (tid < AA){
      float cv = 0.f;
      #pragma unroll
      for (int q=0;q<16;++q) cv += part[q*AA + tid];
      cv /= S;
      s_s[tid] = cv;
      HC[(size_t)m*EE + AA + tid] = cv;
      float cp = __shfl_xor(cv, 1);
      if (!(tid & 1)) s2u[tid>>1] = f2h2(cv, cp);
    }
    __syncthreads();

    // ---- pred needed only if next step is not teacher-forced (never here)
    const bool need_pred = (t+1<TO) && !(u[t+1] < ptf);
    if (need_pred){
      float bvv = -3.4e38f; int bii = 0;
      for (int r=0;r<8;++r){
        int vg = tid*8 + r;
        float a2 = charb[vg];
        const float* er = embW + (size_t)vg*EE;
        for (int e=0;e<AA;++e) a2 += er[e]*s_s[AA+e];       // h part
        for (int e=0;e<AA;++e) a2 += er[AA+e]*s_s[e];       // ctx part
        if (a2 > bvv){ bvv=a2; bii=vg; }
      }
      #pragma unroll
      for (int o=1;o<64;o<<=1){
        float ov = __shfl_xor(bvv,o); int oi = __shfl_xor(bii,o);
        if (ov > bvv || (ov == bvv && oi < bii)){ bvv=ov; bii=oi; }
      }
      if (lane==0){ rv[wvi]=bvv; ri[wvi]=bii; }
      __syncthreads();
      if (tid==0){
        float fv=rv[0]; int fi=ri[0];
        for (int w2=1;w2<16;++w2){
          if (rv[w2]>fv || (rv[w2]==fv && ri[w2]<fi)){ fv=rv[w2]; fi=ri[w2]; }
        }
        pred_s = fi;
      }
      __syncthreads();
    }
  }
}

// ---- logits[m][v] = HC[m][:]·emb[v][:] + char_b[v], fp32 out (B,V,To)
__global__ __launch_bounds__(256) void klogits(const float* __restrict__ HC,
      const float* __restrict__ embW, const float* __restrict__ charb,
      float* __restrict__ out)
{
  __shared__ float Ws[64][68];
  const int vb = blockIdx.x;             // 0..127
  const int mb = blockIdx.y;             // 0..49
  const int tid = threadIdx.x;
  const int m = mb*256 + tid;
  float acc[64];
  #pragma unroll
  for (int i=0;i<64;++i) acc[i]=0.f;
  for (int kc=0; kc<EE; kc+=64){
    {
      int v0 = tid >> 2;
      int q  = tid & 3;
      const float4* src = (const float4*)(embW + (size_t)(vb*64+v0)*EE + kc + q*16);
      float4 a4 = src[0], b4 = src[1], c4 = src[2], d4 = src[3];
      int k0 = q*16;
      Ws[k0+ 0][v0]=a4.x; Ws[k0+ 1][v0]=a4.y; Ws[k0+ 2][v0]=a4.z; Ws[k0+ 3][v0]=a4.w;
      Ws[k0+ 4][v0]=b4.x; Ws[k0+ 5][v0]=b4.y; Ws[k0+ 6][v0]=b4.z; Ws[k0+ 7][v0]=b4.w;
      Ws[k0+ 8][v0]=c4.x; Ws[k0+ 9][v0]=c4.y; Ws[k0+10][v0]=c4.z; Ws[k0+11][v0]=c4.w;
      Ws[k0+12][v0]=d4.x; Ws[k0+13][v0]=d4.y; Ws[k0+14][v0]=d4.z; Ws[k0+15][v0]=d4.w;
    }
    __syncthreads();
    #pragma unroll 4
    for (int kk4=0; kk4<16; ++kk4){
      float4 x4 = *(const float4*)(HC + (size_t)m*EE + kc + kk4*4);
      #pragma unroll
      for (int c=0;c<4;++c){
        float x = (c==0)?x4.x:(c==1)?x4.y:(c==2)?x4.z:x4.w;
        const float4* wr = (const float4*)(&Ws[kk4*4+c][0]);
        #pragma unroll
        for (int i4=0;i4<16;++i4){
          float4 w4 = wr[i4];
          acc[i4*4+0] += x*w4.x; acc[i4*4+1] += x*w4.y;
          acc[i4*4+2] += x*w4.z; acc[i4*4+3] += x*w4.w;
        }
      }
    }
    __syncthreads();
  }
  const int bb = m / TO;
  const int tt = m - bb*TO;
  #pragma unroll 4
  for (int vv2=0; vv2<64; ++vv2){
    int vg = vb*64 + vv2;
    float r = acc[vv2] + charb[vg];
    out[((size_t)bb*VV + vg)*TO + tt] = r;
  }
}

extern "C" void kernel_launch(void* const* d_in, const int* in_sizes, int n_in,
                              void* d_out, int out_size, void* d_ws, size_t ws_size,
                              hipStream_t stream)
{
  const float* k    = (const float*)d_in[0];
  const float* v    = (const float*)d_in[1];
  const int*   enc  = (const int*)d_in[2];
  const int*   gt   = (const int*)d_in[3];
  const void*  ptf  = d_in[4];
  const float* embW = (const float*)d_in[5];
  const float* Wih  = (const float*)d_in[6];
  const float* Whh  = (const float*)d_in[7];
  const float* bih  = (const float*)d_in[8];
  const float* bhh  = (const float*)d_in[9];
  const float* chb  = (const float*)d_in[10];
  const float* u    = (const float*)d_in[11];
  float* out = (float*)d_out;

  float* ws    = (float*)d_ws;
  float* XG    = ws;                        // 12800*1024          = 13107200 f
  float* HC    = XG    + (size_t)MM*G4;     // 12800*512           =  6553600 f
  float* WihxT = HC    + (size_t)MM*EE;     // 512*1024            =   524288 f
  uint*  W2    = (uint*)(WihxT + (size_t)EE*G4);      // 256*1024  =   262144 u
  uint*  kT2   = W2    + (size_t)256*G4;    // 32*128*1024         =  4194304 u
  uint*  v2    = kT2   + (size_t)BB*128*KTP;// 32*512*256          =  4194304 u

  kprep_w  <<<1024, 256, 0, stream>>>(Wih, Whh, W2, WihxT);
  kprep_kv <<<8192, 256, 0, stream>>>(k, v, kT2, v2);
  kxg      <<<dim3(800,4), 256, 0, stream>>>(gt, embW, WihxT, bih, bhh, XG);
  kseq     <<<32, 1024, 0, stream>>>(kT2, v2, enc, ptf, W2, embW, chb, u,
                                     XG, WihxT, bih, bhh, HC);
  klogits  <<<dim3(128,50), 256, 0, stream>>>(HC, embW, chb, out);
}

// Round 5
// 10656.133 us; speedup vs baseline: 2.7062x; 2.7062x over previous
//
#include <hip/hip_runtime.h>
#include <hip/hip_bf16.h>

#define BB 32
#define TD 800
#define TO 400
#define AA 256
#define EE 512
#define VV 8192
#define G4 1024
#define MM (BB*TO)        // 12800
#define NEGE -1e9f
#define KTP 1024          // padded Td (t index) for kT2
#define VTP 512           // padded t2 rows for v2

typedef _Float16 h2_t __attribute__((ext_vector_type(2)));

__device__ __forceinline__ float sigm(float x){ return 1.f/(1.f+expf(-x)); }

__device__ __forceinline__ uint f2h2(float a, float b){
  _Float16 ha = (_Float16)a, hb = (_Float16)b;
  ushort ua = __builtin_bit_cast(ushort, ha), ub = __builtin_bit_cast(ushort, hb);
  return (uint)ua | ((uint)ub << 16);
}

__device__ __forceinline__ float dot2(uint a, uint b, float c){
#if defined(__has_builtin) && __has_builtin(__builtin_amdgcn_fdot2)
  return __builtin_amdgcn_fdot2(__builtin_bit_cast(h2_t, a),
                                __builtin_bit_cast(h2_t, b), c, false);
#else
  h2_t ha = __builtin_bit_cast(h2_t, a), hb = __builtin_bit_cast(h2_t, b);
  return c + (float)ha[0]*(float)hb[0] + (float)ha[1]*(float)hb[1];
#endif
}

__device__ __forceinline__ float decode_ptf(const void* p){
  int w = *(const int*)p;
  if (w >= 0 && w < 1048576) return (float)w;
  return __int_as_float(w);
}

// ---- W2[k2][j] = half2(Wcat[2k2][j], Wcat[2k2+1][j]); Wcat[k][j] = k<256 ? Wih[j][512+k] : Whh[j][k-256]
//      WihxT[e][j] = Wih[j][e]  (fp32, fallback path only)
__global__ void kprep_w(const float* __restrict__ Wih, const float* __restrict__ Whh,
                        uint* __restrict__ W2, float* __restrict__ WihxT){
  int id = blockIdx.x*blockDim.x + threadIdx.x;
  const int total = 256*G4 + EE*G4;
  for (; id < total; id += gridDim.x*blockDim.x){
    if (id < 256*G4){
      int k2 = id >> 10, j = id & 1023;
      int k0 = 2*k2, k1 = 2*k2+1;
      float f0 = (k0 < AA) ? Wih[j*768 + EE + k0] : Whh[j*AA + (k0-AA)];
      float f1 = (k1 < AA) ? Wih[j*768 + EE + k1] : Whh[j*AA + (k1-AA)];
      W2[id] = f2h2(f0, f1);
    } else {
      int i2 = id - 256*G4;
      int e = i2 >> 10, j = i2 & 1023;
      WihxT[i2] = Wih[j*768 + e];
    }
  }
}

// ---- kT2[b][a2][t] = half2(k[b][t][2a2], k[b][t][2a2+1]) padded t<1024
//      v2[b][t2][a]  = half2(v[b][2t2][a], v[b][2t2+1][a]) padded t2<512
__global__ void kprep_kv(const float* __restrict__ k, const float* __restrict__ v,
                         uint* __restrict__ kT2, uint* __restrict__ v2){
  int id = blockIdx.x*blockDim.x + threadIdx.x;
  const int nk = BB*128*KTP;
  const int nv = BB*VTP*AA;
  for (; id < nk + nv; id += gridDim.x*blockDim.x){
    if (id < nk){
      int t = id & (KTP-1);
      int rest = id >> 10;
      int a2 = rest & 127;
      int b = rest >> 7;
      float f0 = 0.f, f1 = 0.f;
      if (t < TD){
        f0 = k[((size_t)b*TD + t)*AA + 2*a2];
        f1 = k[((size_t)b*TD + t)*AA + 2*a2+1];
      }
      kT2[id] = f2h2(f0, f1);
    } else {
      int i2 = id - nk;
      int a = i2 & (AA-1);
      int rest = i2 >> 8;
      int t2 = rest & (VTP-1);
      int b = rest >> 9;
      int t0 = 2*t2, t1 = 2*t2+1;
      float f0 = (t0 < TD) ? v[((size_t)b*TD + t0)*AA + a] : 0.f;
      float f1 = (t1 < TD) ? v[((size_t)b*TD + t1)*AA + a] : 0.f;
      v2[i2] = f2h2(f0, f1);
    }
  }
}

// ---- XG[m][j] = sum_e emb[gt[m]][e]*WihxT[e][j] + b_ih[j] + b_hh[j]   (fp32)
__global__ __launch_bounds__(256) void kxg(const int* __restrict__ gt,
                     const float* __restrict__ embW,
                     const float* __restrict__ WihxT, const float* __restrict__ bih,
                     const float* __restrict__ bhh, float* __restrict__ XG){
  __shared__ float Xs[16][64];
  __shared__ int toks[16];
  const int m0 = blockIdx.x * 16;
  const int j0 = blockIdx.y * 256 + (threadIdx.x & 63)*4;
  const int r0 = (threadIdx.x >> 6) * 4;
  float acc[4][4];
  #pragma unroll
  for (int r=0;r<4;++r){ acc[r][0]=acc[r][1]=acc[r][2]=acc[r][3]=0.f; }
  if (threadIdx.x < 16) toks[threadIdx.x] = gt[m0 + threadIdx.x];
  __syncthreads();
  for (int kc=0; kc<EE; kc+=64){
    {
      int lr = threadIdx.x >> 4;
      int lq = threadIdx.x & 15;
      const float4 xv = *(const float4*)(embW + (size_t)toks[lr]*EE + kc + lq*4);
      Xs[lr][lq*4+0]=xv.x; Xs[lr][lq*4+1]=xv.y; Xs[lr][lq*4+2]=xv.z; Xs[lr][lq*4+3]=xv.w;
    }
    __syncthreads();
    #pragma unroll 4
    for (int kk=0; kk<64; ++kk){
      const float4 wv = *(const float4*)(WihxT + (size_t)(kc+kk)*G4 + j0);
      #pragma unroll
      for (int r=0;r<4;++r){
        float xs = Xs[r0+r][kk];
        acc[r][0] += wv.x*xs; acc[r][1] += wv.y*xs;
        acc[r][2] += wv.z*xs; acc[r][3] += wv.w*xs;
      }
    }
    __syncthreads();
  }
  const float4 b1 = *(const float4*)(bih + j0);
  const float4 b2 = *(const float4*)(bhh + j0);
  #pragma unroll
  for (int r=0;r<4;++r){
    float4 o4 = make_float4(acc[r][0]+b1.x+b2.x, acc[r][1]+b1.y+b2.y,
                            acc[r][2]+b1.z+b2.z, acc[r][3]+b1.w+b2.w);
    *(float4*)(XG + (size_t)(m0+r0+r)*G4 + j0) = o4;
  }
}

// ---- sequential recurrence, one block per batch, f16 dot2 everywhere
__global__ __launch_bounds__(1024, 4) void kseq(
    const uint* __restrict__ kT2, const uint* __restrict__ v2,
    const int* __restrict__ enc, const void* __restrict__ ptfp,
    const uint* __restrict__ W2, const float* __restrict__ embW,
    const float* __restrict__ charb, const float* __restrict__ u,
    const float* __restrict__ XG, const float* __restrict__ WihxT,
    const float* __restrict__ bih, const float* __restrict__ bhh,
    float* __restrict__ HC)
{
  __shared__ float s_s[EE];        // ctx(0..255) || h(256..511)  (fp32, fallback/need_pred)
  __shared__ uint  s2u[256];       // half2 pairs: [0..127]=ctx pairs, [128..255]=h pairs
  __shared__ uint  p2u[512];       // half2 pairs of softmax numerators
  __shared__ float c_s[AA];
  __shared__ float part[4*G4];     // 16KB: gates/energy [4][1024]; ctx [16][256]
  __shared__ float p_s[G4];        // fallback xg buffer only
  __shared__ float x_s[EE];
  __shared__ float red_m[16], red_s[16];
  __shared__ float rv[16];
  __shared__ int   ri[16];
  __shared__ int   pred_s;

  const int b = blockIdx.x;
  const int tid = threadIdx.x;
  const int lane = tid & 63;
  const int wvi = tid >> 6;
  const int len = enc[b];
  const int len2 = (len + 1) >> 1;
  const float ptf = decode_ptf(ptfp);

  if (tid < AA){ s_s[tid]=0.f; s_s[AA+tid]=0.f; c_s[tid]=0.f; s2u[tid]=0u; }
  if (tid == 0) pred_s = 0;
  __syncthreads();

  const int j4 = tid & 255;        // gates: float4-of-j
  const int kq = tid >> 8;         // gates: k2 quarter (64 rows)
  const int tq = tid & 255;        // energy: 4 consecutive t
  const int aq = tid >> 8;         // energy: a2 quarter (32 rows)
  const int a4 = tid & 63;         // ctx: float4-of-a
  const int tg = tid >> 6;         // ctx: t2 group 0..15

  for (int t=0; t<TO; ++t){
    const int m = b*TO + t;
    const bool tf = (u[t] < ptf);

    if (!tf){
      // fallback (never taken with p_tf=1): xg into p_s
      if (tid < EE) x_s[tid] = embW[(size_t)pred_s*EE + tid];
      __syncthreads();
      float a0 = bih[tid] + bhh[tid];
      for (int e=0;e<EE;++e) a0 += x_s[e]*WihxT[(size_t)e*G4 + tid];
      p_s[tid] = a0;
      __syncthreads();
    }

    // ---- gates partials: part[kq][j] = sum over 64 k2-rows of dot2(W2, s2)
    {
      const uint4* wp = (const uint4*)W2 + (size_t)(kq*64)*256 + j4;
      const uint* sp = s2u + kq*64;
      float4 acA = make_float4(0,0,0,0), acB = make_float4(0,0,0,0);
      float4 acC = make_float4(0,0,0,0), acD = make_float4(0,0,0,0);
      #pragma unroll 4
      for (int r=0; r<16; ++r){
        uint4 w0 = wp[0], w1 = wp[256], w2 = wp[512], w3 = wp[768];
        wp += 1024;
        uint s0 = sp[r*4+0], s1 = sp[r*4+1], s2 = sp[r*4+2], s3 = sp[r*4+3];
        acA.x = dot2(w0.x,s0,acA.x); acA.y = dot2(w0.y,s0,acA.y);
        acA.z = dot2(w0.z,s0,acA.z); acA.w = dot2(w0.w,s0,acA.w);
        acB.x = dot2(w1.x,s1,acB.x); acB.y = dot2(w1.y,s1,acB.y);
        acB.z = dot2(w1.z,s1,acB.z); acB.w = dot2(w1.w,s1,acB.w);
        acC.x = dot2(w2.x,s2,acC.x); acC.y = dot2(w2.y,s2,acC.y);
        acC.z = dot2(w2.z,s2,acC.z); acC.w = dot2(w2.w,s2,acC.w);
        acD.x = dot2(w3.x,s3,acD.x); acD.y = dot2(w3.y,s3,acD.y);
        acD.z = dot2(w3.z,s3,acD.z); acD.w = dot2(w3.w,s3,acD.w);
      }
      float4 ac = make_float4(acA.x+acB.x+acC.x+acD.x, acA.y+acB.y+acC.y+acD.y,
                              acA.z+acB.z+acC.z+acD.z, acA.w+acB.w+acC.w+acD.w);
      *(float4*)(part + (size_t)kq*G4 + j4*4) = ac;
    }
    __syncthreads();

    // ---- LSTM pointwise
    if (tid < AA){
      float bi_, bf_, bg_, bo_;
      if (tf){
        const float* xb = XG + (size_t)m*G4;
        bi_ = xb[tid]; bf_ = xb[AA+tid]; bg_ = xb[2*AA+tid]; bo_ = xb[3*AA+tid];
      } else {
        bi_ = p_s[tid]; bf_ = p_s[AA+tid]; bg_ = p_s[2*AA+tid]; bo_ = p_s[3*AA+tid];
      }
      float gi=bi_, gf=bf_, gg=bg_, go=bo_;
      #pragma unroll
      for (int q=0;q<4;++q){
        const float* pp = part + q*G4;
        gi += pp[tid]; gf += pp[AA+tid]; gg += pp[2*AA+tid]; go += pp[3*AA+tid];
      }
      float cn = sigm(gf)*c_s[tid] + sigm(gi)*tanhf(gg);
      float hn = sigm(go)*tanhf(cn);
      c_s[tid] = cn;
      s_s[AA+tid] = hn;
      HC[(size_t)m*EE + tid] = hn;
      float hp = __shfl_xor(hn, 1);
      if (!(tid & 1)) s2u[128 + (tid>>1)] = f2h2(hn, hp);
    }
    __syncthreads();

    // ---- energy partials: part[aq][t'] over 4 consecutive t, 32 a2-rows
    {
      float4 acA = make_float4(0,0,0,0), acB = make_float4(0,0,0,0);
      float4 acC = make_float4(0,0,0,0), acD = make_float4(0,0,0,0);
      if (tq*4 < len){
        const uint4* kp = (const uint4*)kT2 + ((size_t)b*128 + aq*32)*256 + tq;
        const uint* sp = s2u + 128 + aq*32;
        #pragma unroll 4
        for (int r=0; r<8; ++r){
          uint4 k0 = kp[0], k1 = kp[256], k2 = kp[512], k3 = kp[768];
          kp += 1024;
          uint s0 = sp[r*4+0], s1 = sp[r*4+1], s2 = sp[r*4+2], s3 = sp[r*4+3];
          acA.x = dot2(k0.x,s0,acA.x); acA.y = dot2(k0.y,s0,acA.y);
          acA.z = dot2(k0.z,s0,acA.z); acA.w = dot2(k0.w,s0,acA.w);
          acB.x = dot2(k1.x,s1,acB.x); acB.y = dot2(k1.y,s1,acB.y);
          acB.z = dot2(k1.z,s1,acB.z); acB.w = dot2(k1.w,s1,acB.w);
          acC.x = dot2(k2.x,s2,acC.x); acC.y = dot2(k2.y,s2,acC.y);
          acC.z = dot2(k2.z,s2,acC.z); acC.w = dot2(k2.w,s2,acC.w);
          acD.x = dot2(k3.x,s3,acD.x); acD.y = dot2(k3.y,s3,acD.y);
          acD.z = dot2(k3.z,s3,acD.z); acD.w = dot2(k3.w,s3,acD.w);
        }
      }
      float4 ac = make_float4(acA.x+acB.x+acC.x+acD.x, acA.y+acB.y+acC.y+acD.y,
                              acA.z+acB.z+acC.z+acD.z, acA.w+acB.w+acC.w+acD.w);
      *(float4*)(part + (size_t)aq*G4 + tq*4) = ac;
    }
    __syncthreads();

    // ---- softmax over t' = tid
    float ev = NEGE;
    if (tid < len) ev = part[tid] + part[G4+tid] + part[2*G4+tid] + part[3*G4+tid];
    float mx = ev;
    #pragma unroll
    for (int o=1;o<64;o<<=1) mx = fmaxf(mx, __shfl_xor(mx,o));
    if (lane==0) red_m[wvi] = mx;
    __syncthreads();
    float M = red_m[0];
    #pragma unroll
    for (int i2=1;i2<16;++i2) M = fmaxf(M, red_m[i2]);
    float p = expf(ev - M);          // masked -> 0
    float ppart = __shfl_xor(p, 1);
    if (!(tid & 1)) p2u[tid>>1] = f2h2(p, ppart);
    float sv = p;
    #pragma unroll
    for (int o=1;o<64;o<<=1) sv += __shfl_xor(sv,o);
    if (lane==0) red_s[wvi] = sv;
    __syncthreads();
    float S = 0.f;
    #pragma unroll
    for (int i2=0;i2<16;++i2) S += red_s[i2];

    // ---- ctx partials: part[tg][a], dot2 over t-pairs
    {
      float4 ac = make_float4(0,0,0,0);
      const uint4* vp = (const uint4*)v2 + (size_t)b*VTP*64 + a4;
      #pragma unroll 8
      for (int t2=tg; t2<len2; t2+=16){
        uint4 vv = vp[(size_t)t2*64];
        uint pp = p2u[t2];
        ac.x = dot2(vv.x, pp, ac.x); ac.y = dot2(vv.y, pp, ac.y);
        ac.z = dot2(vv.z, pp, ac.z); ac.w = dot2(vv.w, pp, ac.w);
      }
      *(float4*)(part + (size_t)tg*AA + a4*4) = ac;
    }
    __syncthreads();
    if (tid < AA){
      float cv = 0.f;
      #pragma unroll
      for (int q=0;q<16;++q) cv += part[q*AA + tid];
      cv /= S;
      s_s[tid] = cv;
      HC[(size_t)m*EE + AA + tid] = cv;
      float cp = __shfl_xor(cv, 1);
      if (!(tid & 1)) s2u[tid>>1] = f2h2(cv, cp);
    }
    __syncthreads();

    // ---- pred needed only if next step is not teacher-forced (never here)
    const bool need_pred = (t+1<TO) && !(u[t+1] < ptf);
    if (need_pred){
      float bvv = -3.4e38f; int bii = 0;
      for (int r=0;r<8;++r){
        int vg = tid*8 + r;
        float a2 = charb[vg];
        const float* er = embW + (size_t)vg*EE;
        for (int e=0;e<AA;++e) a2 += er[e]*s_s[AA+e];       // h part
        for (int e=0;e<AA;++e) a2 += er[AA+e]*s_s[e];       // ctx part
        if (a2 > bvv){ bvv=a2; bii=vg; }
      }
      #pragma unroll
      for (int o=1;o<64;o<<=1){
        float ov = __shfl_xor(bvv,o); int oi = __shfl_xor(bii,o);
        if (ov > bvv || (ov == bvv && oi < bii)){ bvv=ov; bii=oi; }
      }
      if (lane==0){ rv[wvi]=bvv; ri[wvi]=bii; }
      __syncthreads();
      if (tid==0){
        float fv=rv[0]; int fi=ri[0];
        for (int w2=1;w2<16;++w2){
          if (rv[w2]>fv || (rv[w2]==fv && ri[w2]<fi)){ fv=rv[w2]; fi=ri[w2]; }
        }
        pred_s = fi;
      }
      __syncthreads();
    }
  }
}

// ---- transpose HC[m][e] -> HCT[e][m], 64x64 tiles
__global__ __launch_bounds__(256) void ktrans(const float* __restrict__ HC,
                                              float* __restrict__ HCT){
  __shared__ float tile[64][65];
  const int mb = blockIdx.x;           // 0..199
  const int eb = blockIdx.y;           // 0..7
  const int r  = threadIdx.x >> 4;     // 0..15
  const int cq = threadIdx.x & 15;     // 0..15
  #pragma unroll
  for (int rr=0; rr<64; rr+=16){
    float4 x = *(const float4*)(HC + (size_t)(mb*64+rr+r)*EE + eb*64 + cq*4);
    tile[rr+r][cq*4+0]=x.x; tile[rr+r][cq*4+1]=x.y;
    tile[rr+r][cq*4+2]=x.z; tile[rr+r][cq*4+3]=x.w;
  }
  __syncthreads();
  #pragma unroll
  for (int rr=0; rr<64; rr+=16){
    int e = rr + r;
    float4 y = make_float4(tile[cq*4+0][e], tile[cq*4+1][e],
                           tile[cq*4+2][e], tile[cq*4+3][e]);
    *(float4*)(HCT + (size_t)(eb*64+e)*MM + mb*64 + cq*4) = y;
  }
}

// ---- logits[m][v] = HC[m][:]·emb[v][:] + char_b[v], fp32 out (B,V,To)
//      round-3 structure: column-major HCT reads, no spill
__global__ __launch_bounds__(256) void klogits(const float* __restrict__ HCT,
      const float* __restrict__ embW, const float* __restrict__ charb,
      float* __restrict__ out)
{
  __shared__ float Ws[64][68];           // [kk][v], 16B-aligned rows
  const int vb = blockIdx.x;             // 0..127
  const int mb = blockIdx.y;             // 0..49
  const int tid = threadIdx.x;
  const int m = mb*256 + tid;
  float acc[64];
  #pragma unroll
  for (int i=0;i<64;++i) acc[i]=0.f;
  for (int kc=0; kc<EE; kc+=64){
    {
      int v0 = tid >> 2;
      int q  = tid & 3;
      const float4* src = (const float4*)(embW + (size_t)(vb*64+v0)*EE + kc + q*16);
      float4 a4 = src[0], b4 = src[1], c4 = src[2], d4 = src[3];
      int k0 = q*16;
      Ws[k0+ 0][v0]=a4.x; Ws[k0+ 1][v0]=a4.y; Ws[k0+ 2][v0]=a4.z; Ws[k0+ 3][v0]=a4.w;
      Ws[k0+ 4][v0]=b4.x; Ws[k0+ 5][v0]=b4.y; Ws[k0+ 6][v0]=b4.z; Ws[k0+ 7][v0]=b4.w;
      Ws[k0+ 8][v0]=c4.x; Ws[k0+ 9][v0]=c4.y; Ws[k0+10][v0]=c4.z; Ws[k0+11][v0]=c4.w;
      Ws[k0+12][v0]=d4.x; Ws[k0+13][v0]=d4.y; Ws[k0+14][v0]=d4.z; Ws[k0+15][v0]=d4.w;
    }
    __syncthreads();
    for (int kk=0;kk<64;++kk){
      float x = HCT[(size_t)(kc+kk)*MM + m];
      const float4* wr = (const float4*)(&Ws[kk][0]);
      #pragma unroll
      for (int i4=0;i4<16;++i4){
        float4 w4 = wr[i4];
        acc[i4*4+0] += x*w4.x; acc[i4*4+1] += x*w4.y;
        acc[i4*4+2] += x*w4.z; acc[i4*4+3] += x*w4.w;
      }
    }
    __syncthreads();
  }
  const int bb = m / TO;
  const int tt = m - bb*TO;
  #pragma unroll 4
  for (int vv2=0; vv2<64; ++vv2){
    int vg = vb*64 + vv2;
    float r = acc[vv2] + charb[vg];
    out[((size_t)bb*VV + vg)*TO + tt] = r;
  }
}

extern "C" void kernel_launch(void* const* d_in, const int* in_sizes, int n_in,
                              void* d_out, int out_size, void* d_ws, size_t ws_size,
                              hipStream_t stream)
{
  const float* k    = (const float*)d_in[0];
  const float* v    = (const float*)d_in[1];
  const int*   enc  = (const int*)d_in[2];
  const int*   gt   = (const int*)d_in[3];
  const void*  ptf  = d_in[4];
  const float* embW = (const float*)d_in[5];
  const float* Wih  = (const float*)d_in[6];
  const float* Whh  = (const float*)d_in[7];
  const float* bih  = (const float*)d_in[8];
  const float* bhh  = (const float*)d_in[9];
  const float* chb  = (const float*)d_in[10];
  const float* u    = (const float*)d_in[11];
  float* out = (float*)d_out;

  float* ws    = (float*)d_ws;
  float* XG    = ws;                        // 12800*1024 = 13107200 f
  float* HC    = XG    + (size_t)MM*G4;     // 12800*512  =  6553600 f
  float* WihxT = HC    + (size_t)MM*EE;     // 512*1024   =   524288 f
  uint*  W2    = (uint*)(WihxT + (size_t)EE*G4);      // 256*1024 = 262144 u
  uint*  kT2   = W2    + (size_t)256*G4;    // 32*128*1024 = 4194304 u
  uint*  v2    = kT2   + (size_t)BB*128*KTP;// 32*512*256  = 4194304 u
  float* HCT   = XG;    // aliases XG: XG dead after kseq, HCT born after (stream-ordered)

  kprep_w  <<<1024, 256, 0, stream>>>(Wih, Whh, W2, WihxT);
  kprep_kv <<<8192, 256, 0, stream>>>(k, v, kT2, v2);
  kxg      <<<dim3(800,4), 256, 0, stream>>>(gt, embW, WihxT, bih, bhh, XG);
  kseq     <<<32, 1024, 0, stream>>>(kT2, v2, enc, ptf, W2, embW, chb, u,
                                     XG, WihxT, bih, bhh, HC);
  ktrans   <<<dim3(200,8), 256, 0, stream>>>(HC, HCT);
  klogits  <<<dim3(128,50), 256, 0, stream>>>(HCT, embW, chb, out);
}